// Round 3
// baseline (168.767 us; speedup 1.0000x reference)
//
#include <hip/hip_runtime.h>

// Problem constants (compile-time, from reference):
//   B=2, D=H=W=160, C=2, N_LABELS=25, MAX_LABEL=48
//   voxels/batch V = 160^3 = 4,096,000 ; total voxels = 8,192,000
#define VPB   4096000
#define NLAB  25
#define MAXL  48
#define TOTAL_VOX 8192000

// Native clang vector type — required by __builtin_nontemporal_store
// (HIP's float4 is a class and is rejected).
typedef float vfloat4 __attribute__((ext_vector_type(4)));

// Inverse LUT: FreeSurfer label value -> row index in means/stds.
// GEN_LABELS = {0,2,3,4,5,7,8,10,11,12,13,14,15,16,17,18,24,26,28,41,42,43,44,46,47}
__device__ __constant__ int c_lut[MAXL] = {
    /* 0*/ 0, /* 1*/ 0, /* 2*/ 1, /* 3*/ 2, /* 4*/ 3, /* 5*/ 4, /* 6*/ 0, /* 7*/ 5,
    /* 8*/ 6, /* 9*/ 0, /*10*/ 7, /*11*/ 8, /*12*/ 9, /*13*/10, /*14*/11, /*15*/12,
    /*16*/13, /*17*/14, /*18*/15, /*19*/ 0, /*20*/ 0, /*21*/ 0, /*22*/ 0, /*23*/ 0,
    /*24*/16, /*25*/ 0, /*26*/17, /*27*/ 0, /*28*/18, /*29*/ 0, /*30*/ 0, /*31*/ 0,
    /*32*/ 0, /*33*/ 0, /*34*/ 0, /*35*/ 0, /*36*/ 0, /*37*/ 0, /*38*/ 0, /*39*/ 0,
    /*40*/ 0, /*41*/19, /*42*/20, /*43*/21, /*44*/22, /*45*/ 0, /*46*/23, /*47*/24
};

// One thread handles 8 consecutive voxels (16 output floats).
// Grid: 4000 blocks x 256 threads x 8 voxels = 8,192,000.
__global__ __launch_bounds__(256) void gmm_sample_kernel(
    const int*   __restrict__ labels,   // [B*V] (trailing dim 1 squeezed)
    const float* __restrict__ means,    // [B, 25, 2]
    const float* __restrict__ stds,     // [B, 25, 2]
    const float* __restrict__ noise,    // [B*V, 2]
    float*       __restrict__ out)      // [B*V, 2]
{
    // Fused per-(batch,label-value) table: (mean0, mean1, std0, std1).
    __shared__ float4 table[2 * MAXL];

    const int tid = threadIdx.x;
    if (tid < 2 * MAXL) {
        const int b = tid / MAXL;
        const int v = tid - b * MAXL;
        const int row = c_lut[v];
        const float* mp = means + ((b * NLAB + row) << 1);
        const float* sp = stds  + ((b * NLAB + row) << 1);
        table[tid] = make_float4(mp[0], mp[1], sp[0], sp[1]);
    }
    __syncthreads();

    const int g = blockIdx.x * 256 + tid;           // thread id, < 1,024,000
    const long long v0 = (long long)g << 3;         // first voxel of 8
    // Batch boundary (4,096,000) is a multiple of 8 -> all 8 voxels same batch.
    const int boff = (v0 >= VPB) ? MAXL : 0;

    // Issue all global loads up front for maximum memory-level parallelism.
    const int4* lp = (const int4*)(labels + v0);
    const int4 la = lp[0];
    const int4 lb = lp[1];

    const float4* np4 = (const float4*)(noise + (v0 << 1));
    const float4 n0 = np4[0];
    const float4 n1 = np4[1];
    const float4 n2 = np4[2];
    const float4 n3 = np4[3];

    const float4 e0 = table[boff + la.x];
    const float4 e1 = table[boff + la.y];
    const float4 e2 = table[boff + la.z];
    const float4 e3 = table[boff + la.w];
    const float4 e4 = table[boff + lb.x];
    const float4 e5 = table[boff + lb.y];
    const float4 e6 = table[boff + lb.z];
    const float4 e7 = table[boff + lb.w];

    vfloat4 o0, o1, o2, o3;
    o0.x = fmaf(e0.z, n0.x, e0.x);
    o0.y = fmaf(e0.w, n0.y, e0.y);
    o0.z = fmaf(e1.z, n0.z, e1.x);
    o0.w = fmaf(e1.w, n0.w, e1.y);
    o1.x = fmaf(e2.z, n1.x, e2.x);
    o1.y = fmaf(e2.w, n1.y, e2.y);
    o1.z = fmaf(e3.z, n1.z, e3.x);
    o1.w = fmaf(e3.w, n1.w, e3.y);
    o2.x = fmaf(e4.z, n2.x, e4.x);
    o2.y = fmaf(e4.w, n2.y, e4.y);
    o2.z = fmaf(e5.z, n2.z, e5.x);
    o2.w = fmaf(e5.w, n2.w, e5.y);
    o3.x = fmaf(e6.z, n3.x, e6.x);
    o3.y = fmaf(e6.w, n3.y, e6.y);
    o3.z = fmaf(e7.z, n3.z, e7.x);
    o3.w = fmaf(e7.w, n3.w, e7.y);

    // Output is never re-read: nontemporal stores keep L2/L3 capacity for the
    // input streams (labels/noise largely L3-resident).
    vfloat4* op = (vfloat4*)(out + (v0 << 1));
    __builtin_nontemporal_store(o0, op + 0);
    __builtin_nontemporal_store(o1, op + 1);
    __builtin_nontemporal_store(o2, op + 2);
    __builtin_nontemporal_store(o3, op + 3);
}

extern "C" void kernel_launch(void* const* d_in, const int* in_sizes, int n_in,
                              void* d_out, int out_size, void* d_ws, size_t ws_size,
                              hipStream_t stream) {
    const int*   labels = (const int*)  d_in[0];  // [2,160,160,160,1] int32
    const float* means  = (const float*)d_in[1];  // [2,25,2] f32
    const float* stds   = (const float*)d_in[2];  // [2,25,2] f32
    const float* noise  = (const float*)d_in[3];  // [2,160,160,160,2] f32
    float* out = (float*)d_out;                   // [2,160,160,160,2] f32

    const int threads = 256;
    const int total_threads = TOTAL_VOX / 8;      // 1,024,000
    const int blocks = total_threads / threads;   // 4000
    gmm_sample_kernel<<<blocks, threads, 0, stream>>>(labels, means, stds, noise, out);
}

// Round 4
// 145.166 us; speedup vs baseline: 1.1626x; 1.1626x over previous
//
#include <hip/hip_runtime.h>

// Problem constants (compile-time, from reference):
//   B=2, D=H=W=160, C=2, N_LABELS=25, MAX_LABEL=48
//   voxels/batch V = 160^3 = 4,096,000 ; total voxels = 8,192,000
#define VPB   4096000
#define NLAB  25
#define MAXL  48
#define TOTAL_VOX 8192000

// Inverse LUT: FreeSurfer label value -> row index in means/stds.
// GEN_LABELS = {0,2,3,4,5,7,8,10,11,12,13,14,15,16,17,18,24,26,28,41,42,43,44,46,47}
__device__ __constant__ int c_lut[MAXL] = {
    /* 0*/ 0, /* 1*/ 0, /* 2*/ 1, /* 3*/ 2, /* 4*/ 3, /* 5*/ 4, /* 6*/ 0, /* 7*/ 5,
    /* 8*/ 6, /* 9*/ 0, /*10*/ 7, /*11*/ 8, /*12*/ 9, /*13*/10, /*14*/11, /*15*/12,
    /*16*/13, /*17*/14, /*18*/15, /*19*/ 0, /*20*/ 0, /*21*/ 0, /*22*/ 0, /*23*/ 0,
    /*24*/16, /*25*/ 0, /*26*/17, /*27*/ 0, /*28*/18, /*29*/ 0, /*30*/ 0, /*31*/ 0,
    /*32*/ 0, /*33*/ 0, /*34*/ 0, /*35*/ 0, /*36*/ 0, /*37*/ 0, /*38*/ 0, /*39*/ 0,
    /*40*/ 0, /*41*/19, /*42*/20, /*43*/21, /*44*/22, /*45*/ 0, /*46*/23, /*47*/24
};

// One thread handles 8 consecutive voxels (16 output floats).
// Grid: 4000 blocks x 256 threads x 8 voxels = 8,192,000.
// NOTE (round-3 lesson): nontemporal stores caused 1.74x WRITE_SIZE
// amplification (broken write-combining) — use plain stores.
__global__ __launch_bounds__(256) void gmm_sample_kernel(
    const int*   __restrict__ labels,   // [B*V] (trailing dim 1 squeezed)
    const float* __restrict__ means,    // [B, 25, 2]
    const float* __restrict__ stds,     // [B, 25, 2]
    const float* __restrict__ noise,    // [B*V, 2]
    float*       __restrict__ out)      // [B*V, 2]
{
    // Fused per-(batch,label-value) table: (mean0, mean1, std0, std1).
    __shared__ float4 table[2 * MAXL];

    const int tid = threadIdx.x;
    if (tid < 2 * MAXL) {
        const int b = tid / MAXL;
        const int v = tid - b * MAXL;
        const int row = c_lut[v];
        const float* mp = means + ((b * NLAB + row) << 1);
        const float* sp = stds  + ((b * NLAB + row) << 1);
        table[tid] = make_float4(mp[0], mp[1], sp[0], sp[1]);
    }
    __syncthreads();

    const int g = blockIdx.x * 256 + tid;           // thread id, < 1,024,000
    const long long v0 = (long long)g << 3;         // first voxel of 8
    // Batch boundary (4,096,000) is a multiple of 8 -> all 8 voxels same batch.
    const int boff = (v0 >= VPB) ? MAXL : 0;

    // Issue all global loads up front for maximum memory-level parallelism.
    const int4* lp = (const int4*)(labels + v0);
    const int4 la = lp[0];
    const int4 lb = lp[1];

    const float4* np4 = (const float4*)(noise + (v0 << 1));
    const float4 n0 = np4[0];
    const float4 n1 = np4[1];
    const float4 n2 = np4[2];
    const float4 n3 = np4[3];

    const float4 e0 = table[boff + la.x];
    const float4 e1 = table[boff + la.y];
    const float4 e2 = table[boff + la.z];
    const float4 e3 = table[boff + la.w];
    const float4 e4 = table[boff + lb.x];
    const float4 e5 = table[boff + lb.y];
    const float4 e6 = table[boff + lb.z];
    const float4 e7 = table[boff + lb.w];

    float4 o0, o1, o2, o3;
    o0.x = fmaf(e0.z, n0.x, e0.x);
    o0.y = fmaf(e0.w, n0.y, e0.y);
    o0.z = fmaf(e1.z, n0.z, e1.x);
    o0.w = fmaf(e1.w, n0.w, e1.y);
    o1.x = fmaf(e2.z, n1.x, e2.x);
    o1.y = fmaf(e2.w, n1.y, e2.y);
    o1.z = fmaf(e3.z, n1.z, e3.x);
    o1.w = fmaf(e3.w, n1.w, e3.y);
    o2.x = fmaf(e4.z, n2.x, e4.x);
    o2.y = fmaf(e4.w, n2.y, e4.y);
    o2.z = fmaf(e5.z, n2.z, e5.x);
    o2.w = fmaf(e5.w, n2.w, e5.y);
    o3.x = fmaf(e6.z, n3.x, e6.x);
    o3.y = fmaf(e6.w, n3.y, e6.y);
    o3.z = fmaf(e7.z, n3.z, e7.x);
    o3.w = fmaf(e7.w, n3.w, e7.y);

    float4* op = (float4*)(out + (v0 << 1));
    op[0] = o0;
    op[1] = o1;
    op[2] = o2;
    op[3] = o3;
}

extern "C" void kernel_launch(void* const* d_in, const int* in_sizes, int n_in,
                              void* d_out, int out_size, void* d_ws, size_t ws_size,
                              hipStream_t stream) {
    const int*   labels = (const int*)  d_in[0];  // [2,160,160,160,1] int32
    const float* means  = (const float*)d_in[1];  // [2,25,2] f32
    const float* stds   = (const float*)d_in[2];  // [2,25,2] f32
    const float* noise  = (const float*)d_in[3];  // [2,160,160,160,2] f32
    float* out = (float*)d_out;                   // [2,160,160,160,2] f32

    const int threads = 256;
    const int total_threads = TOTAL_VOX / 8;      // 1,024,000
    const int blocks = total_threads / threads;   // 4000
    gmm_sample_kernel<<<blocks, threads, 0, stream>>>(labels, means, stds, noise, out);
}